// Round 1
// baseline (665.306 us; speedup 1.0000x reference)
//
#include <hip/hip_runtime.h>
#include <math.h>

#define NNODE 22
#define FIN 16
#define C1 128
#define C1P 132   // padded LDS row: 132 % 32 = 4 -> spreads node-rows across banks
#define C2 64
#define C3 32
#define THREADS 256

__global__ __launch_bounds__(THREADS) void gnn_fused(
    const float* __restrict__ x, const float* __restrict__ a,
    const float* __restrict__ w1, const float* __restrict__ b1,
    const float* __restrict__ w2g, const float* __restrict__ w2s,
    const float* __restrict__ b2,
    const float* __restrict__ wf1, const float* __restrict__ bf1,
    const float* __restrict__ wf2, const float* __restrict__ bf2,
    float* __restrict__ out)
{
    const int b = blockIdx.x;
    const int tid = threadIdx.x;

    __shared__ float sA[NNODE * NNODE];   // 484
    __shared__ float sX[NNODE * FIN];     // 352
    __shared__ float sAX[NNODE * FIN];    // 352
    __shared__ float sH1[NNODE][C1P];     // 22 x 132
    __shared__ float sT[NNODE][C1P];      // cols 0..63: h1@w2g ; cols 64..127: h1@w2s
    __shared__ float sH2[NNODE][C2];      // 22 x 64
    __shared__ float sG[C2];
    __shared__ float sG1[C3];

    const float* ga = a + (size_t)b * (NNODE * NNODE);
    const float* gx = x + (size_t)b * (NNODE * FIN);

    for (int i = tid; i < NNODE * NNODE; i += THREADS) sA[i] = ga[i];
    for (int i = tid; i < NNODE * FIN; i += THREADS) sX[i] = gx[i];
    __syncthreads();

    // ---- Phase 1: AX = A @ X   [22,16]  (reassociation: (A@X)@W1 == A@(X@W1))
    for (int i = tid; i < NNODE * FIN; i += THREADS) {
        const int n = i >> 4, k = i & (FIN - 1);
        float s = 0.f;
        #pragma unroll
        for (int m = 0; m < NNODE; ++m) s += sA[n * NNODE + m] * sX[m * FIN + k];
        sAX[i] = s;
    }
    __syncthreads();

    // ---- Phase 2: H1 = relu(AX @ W1 + b1)   [22,128]
    {
        const int c  = tid & (C1 - 1);
        const int g0 = tid >> 7;  // 0 or 1 -> even/odd nodes
        float acc[11];
        #pragma unroll
        for (int j = 0; j < 11; ++j) acc[j] = 0.f;
        #pragma unroll
        for (int k = 0; k < FIN; ++k) {
            const float w = w1[k * C1 + c];
            #pragma unroll
            for (int j = 0; j < 11; ++j) acc[j] += sAX[(g0 + 2 * j) * FIN + k] * w;
        }
        const float bb = b1[c];
        #pragma unroll
        for (int j = 0; j < 11; ++j) {
            const float v = acc[j] + bb;
            sH1[g0 + 2 * j][c] = v > 0.f ? v : 0.f;
        }
    }
    __syncthreads();

    // ---- Phase 3: T[:,0:64] = H1 @ w2g ; T[:,64:128] = H1 @ w2s   (K=128, dominant GEMM)
    {
        const int half = tid >> 7;          // 0: w2g, 1: w2s
        const int cq   = tid & 15;          // column quad: cols cq*4 .. cq*4+3
        const int ng   = (tid >> 4) & 7;    // node group: nodes ng, ng+8, ng+16
        const float* wbase = (half ? w2s : w2g) + cq * 4;
        const int n3 = (ng + 16 < NNODE) ? (ng + 16) : ng;  // clamp; store guarded

        float acc0[4] = {0.f,0.f,0.f,0.f};
        float acc1[4] = {0.f,0.f,0.f,0.f};
        float acc2[4] = {0.f,0.f,0.f,0.f};
        const float* hr0 = &sH1[ng][0];
        const float* hr1 = &sH1[ng + 8][0];
        const float* hr2 = &sH1[n3][0];

        for (int k0 = 0; k0 < C1; k0 += 4) {
            const float4 h0 = *(const float4*)(hr0 + k0);
            const float4 h1v = *(const float4*)(hr1 + k0);
            const float4 h2v = *(const float4*)(hr2 + k0);
            #pragma unroll
            for (int kk = 0; kk < 4; ++kk) {
                const float4 w = *(const float4*)(wbase + (size_t)(k0 + kk) * C2);
                const float e0 = ((const float*)&h0)[kk];
                const float e1 = ((const float*)&h1v)[kk];
                const float e2 = ((const float*)&h2v)[kk];
                acc0[0] += e0 * w.x; acc0[1] += e0 * w.y; acc0[2] += e0 * w.z; acc0[3] += e0 * w.w;
                acc1[0] += e1 * w.x; acc1[1] += e1 * w.y; acc1[2] += e1 * w.z; acc1[3] += e1 * w.w;
                acc2[0] += e2 * w.x; acc2[1] += e2 * w.y; acc2[2] += e2 * w.z; acc2[3] += e2 * w.w;
            }
        }
        const int c0 = half * C2 + cq * 4;
        *(float4*)&sT[ng][c0]     = make_float4(acc0[0], acc0[1], acc0[2], acc0[3]);
        *(float4*)&sT[ng + 8][c0] = make_float4(acc1[0], acc1[1], acc1[2], acc1[3]);
        if (ng < 6)
            *(float4*)&sT[ng + 16][c0] = make_float4(acc2[0], acc2[1], acc2[2], acc2[3]);
    }
    __syncthreads();

    // ---- Phase 4: H2 = relu(A @ T[:,0:64] + T[:,64:128] + b2)   [22,64]
    {
        const int c2 = tid & (C2 - 1);
        const int g4 = tid >> 6;  // 0..3
        float tcol[NNODE];
        #pragma unroll
        for (int m = 0; m < NNODE; ++m) tcol[m] = sT[m][c2];
        const float bb = b2[c2];
        for (int n = g4; n < NNODE; n += 4) {
            float s = bb + sT[n][C2 + c2];
            #pragma unroll
            for (int m = 0; m < NNODE; ++m) s += sA[n * NNODE + m] * tcol[m];
            sH2[n][c2] = s > 0.f ? s : 0.f;
        }
    }
    __syncthreads();

    // ---- Phase 5: global sum pool   g[c2] = sum_n H2[n][c2]
    if (tid < C2) {
        float s = 0.f;
        #pragma unroll
        for (int n = 0; n < NNODE; ++n) s += sH2[n][tid];
        sG[tid] = s;
    }
    __syncthreads();

    // ---- Phase 6: head  g1 = relu(g @ wf1 + bf1);  out = sigmoid(g1 @ wf2 + bf2)
    if (tid < C3) {
        float s = bf1[tid];
        #pragma unroll
        for (int c = 0; c < C2; ++c) s += sG[c] * wf1[c * C3 + tid];
        sG1[tid] = s > 0.f ? s : 0.f;
    }
    __syncthreads();
    if (tid == 0) {
        float s = bf2[0];
        #pragma unroll
        for (int j = 0; j < C3; ++j) s += sG1[j] * wf2[j];
        out[b] = 1.f / (1.f + expf(-s));
    }
}

extern "C" void kernel_launch(void* const* d_in, const int* in_sizes, int n_in,
                              void* d_out, int out_size, void* d_ws, size_t ws_size,
                              hipStream_t stream) {
    const float* x   = (const float*)d_in[0];
    const float* a   = (const float*)d_in[1];
    const float* w1  = (const float*)d_in[2];
    const float* b1  = (const float*)d_in[3];
    const float* w2g = (const float*)d_in[4];
    const float* w2s = (const float*)d_in[5];
    const float* b2  = (const float*)d_in[6];
    const float* wf1 = (const float*)d_in[7];
    const float* bf1 = (const float*)d_in[8];
    const float* wf2 = (const float*)d_in[9];
    const float* bf2 = (const float*)d_in[10];
    float* out = (float*)d_out;

    const int B = in_sizes[0] / (NNODE * FIN);  // 32768
    gnn_fused<<<dim3(B), dim3(THREADS), 0, stream>>>(
        x, a, w1, b1, w2g, w2s, b2, wf1, bf1, wf2, bf2, out);
}

// Round 3
// 337.628 us; speedup vs baseline: 1.9705x; 1.9705x over previous
//
#include <hip/hip_runtime.h>
#include <math.h>

#define NNODE 22
#define FIN 16
#define C1 128
#define C2 64
#define C3 32
#define GPB 4              // graphs per block
#define RROWS (GPB*NNODE)  // 88 valid rows
#define RP 96              // 6 M-tiles of 16
#define THREADS 256

typedef __attribute__((ext_vector_type(8))) short short8;
typedef __attribute__((ext_vector_type(4))) float f32x4;

__device__ __forceinline__ unsigned short f2bf(float f){
    unsigned int u = __builtin_bit_cast(unsigned int, f);
    u += 0x7fffu + ((u >> 16) & 1u);          // RNE
    return (unsigned short)(u >> 16);
}
__device__ __forceinline__ float bf2f(unsigned short h){
    unsigned int u = ((unsigned int)h) << 16;
    return __builtin_bit_cast(float, u);
}
// split f = hi + lo with bf16 hi, lo  ->  ~2^-17 relative accuracy
__device__ __forceinline__ void fsplit(float f, unsigned short& hi, unsigned short& lo){
    hi = f2bf(f);
    lo = f2bf(f - bf2f(hi));
}
// T2 XOR-swizzle: kills 16-way bank conflict on 256B-stride ds_read_b128
__device__ __forceinline__ unsigned short* hadr(unsigned char* base, int r, int c){
    return (unsigned short*)(base + r*(C1*2) + (((c*2) ^ ((r & 7) << 4))));
}

union UHi {
    float x[GPB*NNODE*FIN];      // phase 0-1: X staging
    unsigned char h[RP*C1*2];    // phase 2+: H1_hi, then T_hi (bf16, swizzled)
};

__global__ __launch_bounds__(THREADS, 2) void gnn_fused(
    const float* __restrict__ x, const float* __restrict__ a,
    const float* __restrict__ w1, const float* __restrict__ b1,
    const float* __restrict__ w2g, const float* __restrict__ w2s,
    const float* __restrict__ b2,
    const float* __restrict__ wf1, const float* __restrict__ bf1,
    const float* __restrict__ wf2, const float* __restrict__ bf2,
    float* __restrict__ out)
{
    __shared__ float sA[GPB*NNODE*NNODE];        // 7744 B
    __shared__ UHi Uhi;                          // 24576 B
    __shared__ unsigned char sLo[RP*C1*2];       // 24576 B: H1_lo, then T_lo
    __shared__ unsigned short sAXhi[RP][FIN];    // 3072 B
    __shared__ unsigned short sAXlo[RP][FIN];    // 3072 B
    __shared__ float sPool[GPB][C2];             // 1024 B
    __shared__ float sG1[GPB][C3];               // 512 B

    const int tid  = threadIdx.x;
    const int lane = tid & 63;
    const int wv   = tid >> 6;    // wave 0..3 -> 32-col slice / graph id
    const int lr   = lane & 15;   // row-in-tile (A) / col-in-tile (B,D)
    const int lg   = lane >> 4;   // k-group 0..3

    // ---- W2 B-fragments hi/lo in registers (cols 0-63 = w2g, 64-127 = w2s) ----
    short8 b2h[2][4], b2l[2][4];
    #pragma unroll
    for (int nt = 0; nt < 2; ++nt) {
        const int col = wv*32 + nt*16 + lr;
        const float* wsrc = (col < C2) ? (w2g + col) : (w2s + (col - C2));
        #pragma unroll
        for (int kt = 0; kt < 4; ++kt) {
            short8 fh, fl;
            #pragma unroll
            for (int e = 0; e < 8; ++e) {
                unsigned short hh, ll;
                fsplit(wsrc[(size_t)(kt*32 + lg*8 + e) * C2], hh, ll);
                fh[e] = (short)hh; fl[e] = (short)ll;
            }
            b2h[nt][kt] = fh; b2l[nt][kt] = fl;
        }
    }
    // ---- W1 B-fragments hi/lo (K=16 padded to 32: lanes>=32 zero) ----
    short8 b1h[2], b1l[2];
    #pragma unroll
    for (int nt = 0; nt < 2; ++nt) {
        short8 fh = {0,0,0,0,0,0,0,0}, fl = {0,0,0,0,0,0,0,0};
        if (lane < 32) {
            const int col = wv*32 + nt*16 + lr;
            #pragma unroll
            for (int e = 0; e < 8; ++e) {
                unsigned short hh, ll;
                fsplit(w1[(size_t)(lg*8 + e) * C1 + col], hh, ll);
                fh[e] = (short)hh; fl[e] = (short)ll;
            }
        }
        b1h[nt] = fh; b1l[nt] = fl;
    }
    float bb1[2];
    bb1[0] = b1[wv*32 + lr];
    bb1[1] = b1[wv*32 + 16 + lr];

    // ---- stage A and X ----
    const float* ga = a + (size_t)blockIdx.x * (GPB*NNODE*NNODE);
    const float* gx = x + (size_t)blockIdx.x * (GPB*NNODE*FIN);
    for (int i = tid; i < GPB*NNODE*NNODE; i += THREADS) sA[i] = ga[i];
    for (int i = tid; i < GPB*NNODE*FIN;  i += THREADS) Uhi.x[i] = gx[i];
    __syncthreads();

    // ---- Phase 1: AX = A @ X  (fp32 VALU), store hi/lo bf16 ----
    for (int i = tid; i < GPB*NNODE*FIN; i += THREADS) {
        const int g = i / (NNODE*FIN);
        const int r = i - g*(NNODE*FIN);
        const int n = r >> 4, k = r & 15;
        const float* Ag = sA + g*(NNODE*NNODE) + n*NNODE;
        const float* Xg = Uhi.x + g*(NNODE*FIN) + k;
        float s = 0.f;
        #pragma unroll
        for (int m = 0; m < NNODE; ++m) s += Ag[m] * Xg[m*FIN];
        unsigned short hh, ll;
        fsplit(s, hh, ll);
        sAXhi[g*NNODE + n][k] = hh;
        sAXlo[g*NNODE + n][k] = ll;
    }
    __syncthreads();

    // ---- Phase 2: H1 = relu(AX @ W1 + b1)  3-product MFMA -> hi/lo LDS ----
    {
        #pragma unroll
        for (int mt = 0; mt < 6; ++mt) {
            short8 ah = {0,0,0,0,0,0,0,0}, al = {0,0,0,0,0,0,0,0};
            if (lane < 32) {
                ah = *(const short8*)&sAXhi[mt*16 + lr][lg*8];
                al = *(const short8*)&sAXlo[mt*16 + lr][lg*8];
            }
            f32x4 a0 = {0.f,0.f,0.f,0.f}, a1 = {0.f,0.f,0.f,0.f};
            a0 = __builtin_amdgcn_mfma_f32_16x16x32_bf16(ah, b1h[0], a0, 0, 0, 0);
            a0 = __builtin_amdgcn_mfma_f32_16x16x32_bf16(ah, b1l[0], a0, 0, 0, 0);
            a0 = __builtin_amdgcn_mfma_f32_16x16x32_bf16(al, b1h[0], a0, 0, 0, 0);
            a1 = __builtin_amdgcn_mfma_f32_16x16x32_bf16(ah, b1h[1], a1, 0, 0, 0);
            a1 = __builtin_amdgcn_mfma_f32_16x16x32_bf16(ah, b1l[1], a1, 0, 0, 0);
            a1 = __builtin_amdgcn_mfma_f32_16x16x32_bf16(al, b1h[1], a1, 0, 0, 0);
            #pragma unroll
            for (int r = 0; r < 4; ++r) {
                const int row = mt*16 + lg*4 + r;
                if (row < RROWS) {
                    float v0 = a0[r] + bb1[0]; v0 = v0 > 0.f ? v0 : 0.f;
                    float v1 = a1[r] + bb1[1]; v1 = v1 > 0.f ? v1 : 0.f;
                    unsigned short hh, ll;
                    fsplit(v0, hh, ll);
                    *hadr(Uhi.h, row, wv*32 + lr) = hh;
                    *hadr(sLo,   row, wv*32 + lr) = ll;
                    fsplit(v1, hh, ll);
                    *hadr(Uhi.h, row, wv*32 + 16 + lr) = hh;
                    *hadr(sLo,   row, wv*32 + 16 + lr) = ll;
                }
            }
        }
    }
    __syncthreads();

    // ---- Phase 3: T = H1 @ [w2g | w2s]  3-product MFMA (dominant GEMM) ----
    {
        f32x4 acc[6][2];
        #pragma unroll
        for (int mt = 0; mt < 6; ++mt) {
            acc[mt][0] = (f32x4){0.f,0.f,0.f,0.f};
            acc[mt][1] = (f32x4){0.f,0.f,0.f,0.f};
        }
        const int swz = (lr & 7) << 4;   // row&7 == lr&7 (mt*16 ≡ 0 mod 8)
        #pragma unroll
        for (int kt = 0; kt < 4; ++kt) {
            #pragma unroll
            for (int mt = 0; mt < 6; ++mt) {
                const int row = mt*16 + lr;
                const int boff = row*(C1*2) + (((kt*32 + lg*8)*2) ^ swz);
                short8 ah = *(const short8*)(Uhi.h + boff);
                short8 al = *(const short8*)(sLo   + boff);
                acc[mt][0] = __builtin_amdgcn_mfma_f32_16x16x32_bf16(ah, b2h[0][kt], acc[mt][0], 0, 0, 0);
                acc[mt][0] = __builtin_amdgcn_mfma_f32_16x16x32_bf16(ah, b2l[0][kt], acc[mt][0], 0, 0, 0);
                acc[mt][0] = __builtin_amdgcn_mfma_f32_16x16x32_bf16(al, b2h[0][kt], acc[mt][0], 0, 0, 0);
                acc[mt][1] = __builtin_amdgcn_mfma_f32_16x16x32_bf16(ah, b2h[1][kt], acc[mt][1], 0, 0, 0);
                acc[mt][1] = __builtin_amdgcn_mfma_f32_16x16x32_bf16(ah, b2l[1][kt], acc[mt][1], 0, 0, 0);
                acc[mt][1] = __builtin_amdgcn_mfma_f32_16x16x32_bf16(al, b2h[1][kt], acc[mt][1], 0, 0, 0);
            }
        }
        __syncthreads();   // all waves done READING H1 before overwrite with T
        #pragma unroll
        for (int mt = 0; mt < 6; ++mt) {
            #pragma unroll
            for (int r = 0; r < 4; ++r) {
                const int row = mt*16 + lg*4 + r;
                if (row < RROWS) {
                    unsigned short hh, ll;
                    fsplit(acc[mt][0][r], hh, ll);
                    *hadr(Uhi.h, row, wv*32 + lr) = hh;
                    *hadr(sLo,   row, wv*32 + lr) = ll;
                    fsplit(acc[mt][1][r], hh, ll);
                    *hadr(Uhi.h, row, wv*32 + 16 + lr) = hh;
                    *hadr(sLo,   row, wv*32 + 16 + lr) = ll;
                }
            }
        }
    }
    __syncthreads();

    // ---- Phase 4+5: H2 = relu(A@Tg + Ts + b2); pool (fp32, T = hi+lo) ----
    {
        const int g = wv, c = lane;       // one wave per graph, one lane per col
        float tg[NNODE];
        #pragma unroll
        for (int m = 0; m < NNODE; ++m)
            tg[m] = bf2f(*hadr(Uhi.h, g*NNODE + m, c)) + bf2f(*hadr(sLo, g*NNODE + m, c));
        const float bb = b2[c];
        const float* Ag = sA + g*(NNODE*NNODE);
        float pool = 0.f;
        #pragma unroll
        for (int n = 0; n < NNODE; ++n) {
            float s = bb + bf2f(*hadr(Uhi.h, g*NNODE + n, C2 + c))
                         + bf2f(*hadr(sLo,   g*NNODE + n, C2 + c));
            #pragma unroll
            for (int m = 0; m < NNODE; ++m) s += Ag[n*NNODE + m] * tg[m];
            pool += (s > 0.f ? s : 0.f);
        }
        sPool[g][c] = pool;
    }
    __syncthreads();

    // ---- Phase 6: head (fp32) ----
    if (tid < GPB*C3) {
        const int g = tid >> 5, j = tid & 31;
        float s = bf1[j];
        #pragma unroll
        for (int c = 0; c < C2; ++c) s += sPool[g][c] * wf1[c*C3 + j];
        sG1[g][j] = s > 0.f ? s : 0.f;
    }
    __syncthreads();
    if (tid < GPB) {
        float s = bf2[0];
        #pragma unroll
        for (int j = 0; j < C3; ++j) s += sG1[tid][j] * wf2[j];
        out[(size_t)blockIdx.x*GPB + tid] = 1.f / (1.f + expf(-s));
    }
}

extern "C" void kernel_launch(void* const* d_in, const int* in_sizes, int n_in,
                              void* d_out, int out_size, void* d_ws, size_t ws_size,
                              hipStream_t stream) {
    const float* x   = (const float*)d_in[0];
    const float* a   = (const float*)d_in[1];
    const float* w1  = (const float*)d_in[2];
    const float* b1  = (const float*)d_in[3];
    const float* w2g = (const float*)d_in[4];
    const float* w2s = (const float*)d_in[5];
    const float* b2  = (const float*)d_in[6];
    const float* wf1 = (const float*)d_in[7];
    const float* bf1 = (const float*)d_in[8];
    const float* wf2 = (const float*)d_in[9];
    const float* bf2 = (const float*)d_in[10];
    float* out = (float*)d_out;

    const int B = in_sizes[0] / (NNODE * FIN);  // 32768
    gnn_fused<<<dim3(B / GPB), dim3(THREADS), 0, stream>>>(
        x, a, w1, b1, w2g, w2s, b2, wf1, bf1, wf2, bf2, out);
}

// Round 4
// 234.083 us; speedup vs baseline: 2.8422x; 1.4423x over previous
//
#include <hip/hip_runtime.h>
#include <math.h>

#define NNODE 22
#define FIN 16
#define C1 128
#define C2 64
#define C3 32
#define GPB 2              // graphs per block
#define RROWS (GPB*NNODE)  // 44 valid rows
#define RP 48              // 3 M-tiles of 16
#define MT 3
#define THREADS 256

typedef __attribute__((ext_vector_type(8))) short short8;
typedef __attribute__((ext_vector_type(4))) float f32x4;

// ws layout: W2 frags: 64 frags (wv,nt,kt,h) x 64 lanes x 16B = 65536 B @ 0
//            W1 frags: 16 frags (wv,nt,h)    x 64 lanes x 16B = 16384 B @ 65536
#define WS2_BYTES (64*64*16)
#define WS1_OFF   WS2_BYTES

__device__ __forceinline__ unsigned short f2bf(float f){
    unsigned int u = __builtin_bit_cast(unsigned int, f);
    u += 0x7fffu + ((u >> 16) & 1u);          // RNE
    return (unsigned short)(u >> 16);
}
__device__ __forceinline__ float bf2f(unsigned short h){
    unsigned int u = ((unsigned int)h) << 16;
    return __builtin_bit_cast(float, u);
}
__device__ __forceinline__ void fsplit(float f, unsigned short& hi, unsigned short& lo){
    hi = f2bf(f);
    lo = f2bf(f - bf2f(hi));
}
// T2 XOR-swizzle for the bf16 H1 buffer (256B row stride)
__device__ __forceinline__ unsigned short* hadr(unsigned char* base, int r, int c){
    return (unsigned short*)(base + r*(C1*2) + (((c*2) ^ ((r & 7) << 4))));
}

// ---------------- setup kernel: split weights into MFMA fragments once ----------
__global__ void prep_frags(const float* __restrict__ w1,
                           const float* __restrict__ w2g,
                           const float* __restrict__ w2s,
                           unsigned char* __restrict__ ws)
{
    const int t = blockIdx.x * 256 + threadIdx.x;   // 0..5119
    if (t < 4096) {                                  // W2: f = ((wv*2+nt)*4+kt)*2+h
        const int lane = t & 63, f = t >> 6;
        const int h = f & 1, kt = (f >> 1) & 3, nt = (f >> 3) & 1, wv = f >> 4;
        const int lr = lane & 15, lg = lane >> 4;
        const int col = wv*32 + nt*16 + lr;
        const float* src = (col < C2) ? (w2g + col) : (w2s + (col - C2));
        short8 out;
        #pragma unroll
        for (int e = 0; e < 8; ++e) {
            unsigned short hh, ll;
            fsplit(src[(size_t)(kt*32 + lg*8 + e) * C2], hh, ll);
            out[e] = (short)(h ? ll : hh);
        }
        *(short8*)(ws + (size_t)f*1024 + lane*16) = out;
    } else if (t < 5120) {                           // W1: f = (wv*2+nt)*2+h
        const int u = t - 4096;
        const int lane = u & 63, f = u >> 6;
        const int h = f & 1, nt = (f >> 1) & 1, wv = f >> 2;
        const int lr = lane & 15, lg = lane >> 4;
        short8 out = {0,0,0,0,0,0,0,0};
        if (lane < 32) {
            const int col = wv*32 + nt*16 + lr;
            #pragma unroll
            for (int e = 0; e < 8; ++e) {
                unsigned short hh, ll;
                fsplit(w1[(size_t)(lg*8 + e) * C1 + col], hh, ll);
                out[e] = (short)(h ? ll : hh);
            }
        }
        *(short8*)(ws + WS1_OFF + (size_t)f*1024 + lane*16) = out;
    }
}

// ---------------- main fused kernel ----------------
union Ubuf {
    float x[GPB*NNODE*FIN];                                            // 2816 B (stage->p1)
    struct { unsigned char hi[RP*C1*2]; unsigned char lo[RP*C1*2]; } h1; // 24576 B (p2->p3)
    float t[RP][C1];                                                   // 24576 B (p3->p5)
};

__global__ __launch_bounds__(THREADS, 4) void gnn_fused(
    const float* __restrict__ x, const float* __restrict__ a,
    const float* __restrict__ b1, const float* __restrict__ b2,
    const float* __restrict__ wf1, const float* __restrict__ bf1,
    const float* __restrict__ wf2, const float* __restrict__ bf2,
    const unsigned char* __restrict__ ws,
    float* __restrict__ out)
{
    __shared__ float sA[GPB*NNODE*NNODE];        // 3872 B
    __shared__ Ubuf U;                           // 24576 B
    __shared__ unsigned short sAXhi[RP][FIN];    // 1536 B
    __shared__ unsigned short sAXlo[RP][FIN];    // 1536 B
    __shared__ float sPoolP[4][C2];              // 1024 B
    __shared__ float sG1[GPB][C3];               // 256 B

    const int tid  = threadIdx.x;
    const int lane = tid & 63;
    const int wv   = tid >> 6;    // wave -> 32-col slice
    const int lr   = lane & 15;
    const int lg   = lane >> 4;

    // ---- stage A, X (float4) ----
    const float* ga = a + (size_t)blockIdx.x * (GPB*NNODE*NNODE);
    const float* gx = x + (size_t)blockIdx.x * (GPB*NNODE*FIN);
    if (tid < (GPB*NNODE*NNODE)/4) ((float4*)sA)[tid] = ((const float4*)ga)[tid];
    if (tid < (GPB*NNODE*FIN)/4)  ((float4*)U.x)[tid] = ((const float4*)gx)[tid];
    __syncthreads();

    // ---- Phase 1: AX = A @ X (fp32 VALU) -> hi/lo bf16 ----
    for (int i = tid; i < GPB*NNODE*FIN; i += THREADS) {
        const int g = i / (NNODE*FIN);
        const int r = i - g*(NNODE*FIN);
        const int n = r >> 4, k = r & 15;
        const float* Ag = sA + g*(NNODE*NNODE) + n*NNODE;
        const float* Xg = U.x + g*(NNODE*FIN) + k;
        float s = 0.f;
        #pragma unroll
        for (int m = 0; m < NNODE; ++m) s += Ag[m] * Xg[m*FIN];
        unsigned short hh, ll;
        fsplit(s, hh, ll);
        sAXhi[g*NNODE + n][k] = hh;
        sAXlo[g*NNODE + n][k] = ll;
    }
    __syncthreads();

    // ---- Phase 2: H1 = relu(AX @ W1 + b1) via bf16x3 MFMA -> hi/lo LDS ----
    {
        const unsigned char* w1f = ws + WS1_OFF + (size_t)wv*4096 + lane*16;
        const short8 b1h0 = *(const short8*)(w1f + 0);
        const short8 b1l0 = *(const short8*)(w1f + 1024);
        const short8 b1h1 = *(const short8*)(w1f + 2048);
        const short8 b1l1 = *(const short8*)(w1f + 3072);
        const float bb10 = b1[wv*32 + lr];
        const float bb11 = b1[wv*32 + 16 + lr];
        #pragma unroll
        for (int mt = 0; mt < MT; ++mt) {
            short8 ah = {0,0,0,0,0,0,0,0}, al = {0,0,0,0,0,0,0,0};
            if (lane < 32) {
                ah = *(const short8*)&sAXhi[mt*16 + lr][lg*8];
                al = *(const short8*)&sAXlo[mt*16 + lr][lg*8];
            }
            f32x4 a0 = {0.f,0.f,0.f,0.f}, a1 = {0.f,0.f,0.f,0.f};
            a0 = __builtin_amdgcn_mfma_f32_16x16x32_bf16(ah, b1h0, a0, 0, 0, 0);
            a0 = __builtin_amdgcn_mfma_f32_16x16x32_bf16(ah, b1l0, a0, 0, 0, 0);
            a0 = __builtin_amdgcn_mfma_f32_16x16x32_bf16(al, b1h0, a0, 0, 0, 0);
            a1 = __builtin_amdgcn_mfma_f32_16x16x32_bf16(ah, b1h1, a1, 0, 0, 0);
            a1 = __builtin_amdgcn_mfma_f32_16x16x32_bf16(ah, b1l1, a1, 0, 0, 0);
            a1 = __builtin_amdgcn_mfma_f32_16x16x32_bf16(al, b1h1, a1, 0, 0, 0);
            #pragma unroll
            for (int r = 0; r < 4; ++r) {
                const int row = mt*16 + lg*4 + r;
                if (row < RROWS) {
                    float v0 = a0[r] + bb10; v0 = v0 > 0.f ? v0 : 0.f;
                    float v1 = a1[r] + bb11; v1 = v1 > 0.f ? v1 : 0.f;
                    unsigned short hh, ll;
                    fsplit(v0, hh, ll);
                    *hadr(U.h1.hi, row, wv*32 + lr) = hh;
                    *hadr(U.h1.lo, row, wv*32 + lr) = ll;
                    fsplit(v1, hh, ll);
                    *hadr(U.h1.hi, row, wv*32 + 16 + lr) = hh;
                    *hadr(U.h1.lo, row, wv*32 + 16 + lr) = ll;
                }
            }
        }
    }
    __syncthreads();

    // ---- Phase 3: T = H1 @ [w2g|w2s] via bf16x3 MFMA, W frags from L2-hot ws ----
    {
        f32x4 acc[MT][2];
        #pragma unroll
        for (int mt = 0; mt < MT; ++mt) {
            acc[mt][0] = (f32x4){0.f,0.f,0.f,0.f};
            acc[mt][1] = (f32x4){0.f,0.f,0.f,0.f};
        }
        const unsigned char* w2f = ws + (size_t)wv*16384 + lane*16;
        const int swz = (lr & 7) << 4;
        #pragma unroll
        for (int kt = 0; kt < 4; ++kt) {
            const unsigned char* wk = w2f + kt*2048;
            const short8 w0h = *(const short8*)(wk + 0);
            const short8 w0l = *(const short8*)(wk + 1024);
            const short8 w1h_ = *(const short8*)(wk + 8192);
            const short8 w1l_ = *(const short8*)(wk + 8192 + 1024);
            #pragma unroll
            for (int mt = 0; mt < MT; ++mt) {
                const int row = mt*16 + lr;
                const int boff = row*(C1*2) + (((kt*32 + lg*8)*2) ^ swz);
                const short8 ah = *(const short8*)(U.h1.hi + boff);
                const short8 al = *(const short8*)(U.h1.lo + boff);
                acc[mt][0] = __builtin_amdgcn_mfma_f32_16x16x32_bf16(ah, w0h, acc[mt][0], 0, 0, 0);
                acc[mt][0] = __builtin_amdgcn_mfma_f32_16x16x32_bf16(ah, w0l, acc[mt][0], 0, 0, 0);
                acc[mt][0] = __builtin_amdgcn_mfma_f32_16x16x32_bf16(al, w0h, acc[mt][0], 0, 0, 0);
                acc[mt][1] = __builtin_amdgcn_mfma_f32_16x16x32_bf16(ah, w1h_, acc[mt][1], 0, 0, 0);
                acc[mt][1] = __builtin_amdgcn_mfma_f32_16x16x32_bf16(ah, w1l_, acc[mt][1], 0, 0, 0);
                acc[mt][1] = __builtin_amdgcn_mfma_f32_16x16x32_bf16(al, w1h_, acc[mt][1], 0, 0, 0);
            }
        }
        __syncthreads();   // all waves done READING H1 before overwrite with fp32 T
        #pragma unroll
        for (int mt = 0; mt < MT; ++mt) {
            #pragma unroll
            for (int r = 0; r < 4; ++r) {
                const int row = mt*16 + lg*4 + r;
                if (row < RROWS) {
                    U.t[row][wv*32 + lr]      = acc[mt][0][r];
                    U.t[row][wv*32 + 16 + lr] = acc[mt][1][r];
                }
            }
        }
    }
    __syncthreads();

    // ---- Phase 4+5: H2 = relu(A@Tg + Ts + b2); pool.  2 waves per graph ----
    {
        const int g = wv >> 1, half = wv & 1;
        const int c = lane;
        float tg[NNODE];
        #pragma unroll
        for (int m = 0; m < NNODE; ++m) tg[m] = U.t[g*NNODE + m][c];
        const float bb = b2[c];
        float pool = 0.f;
        for (int n = half*11; n < half*11 + 11; ++n) {
            float s = bb + U.t[g*NNODE + n][C2 + c];
            const float2* A2 = (const float2*)(sA + g*(NNODE*NNODE) + n*NNODE);
            #pragma unroll
            for (int m2 = 0; m2 < 11; ++m2) {
                const float2 av = A2[m2];
                s += av.x * tg[2*m2] + av.y * tg[2*m2 + 1];
            }
            pool += (s > 0.f ? s : 0.f);
        }
        sPoolP[wv][c] = pool;
    }
    __syncthreads();

    // ---- Phase 6: head ----
    if (tid < GPB*C3) {
        const int g = tid >> 5, j = tid & 31;
        float s = bf1[j];
        #pragma unroll
        for (int c = 0; c < C2; ++c)
            s += (sPoolP[2*g][c] + sPoolP[2*g + 1][c]) * wf1[c*C3 + j];
        sG1[g][j] = s > 0.f ? s : 0.f;
    }
    __syncthreads();
    if (tid < GPB) {
        float s = bf2[0];
        #pragma unroll
        for (int j = 0; j < C3; ++j) s += sG1[tid][j] * wf2[j];
        out[(size_t)blockIdx.x*GPB + tid] = 1.f / (1.f + expf(-s));
    }
}

extern "C" void kernel_launch(void* const* d_in, const int* in_sizes, int n_in,
                              void* d_out, int out_size, void* d_ws, size_t ws_size,
                              hipStream_t stream) {
    const float* x   = (const float*)d_in[0];
    const float* a   = (const float*)d_in[1];
    const float* w1  = (const float*)d_in[2];
    const float* b1  = (const float*)d_in[3];
    const float* w2g = (const float*)d_in[4];
    const float* w2s = (const float*)d_in[5];
    const float* b2  = (const float*)d_in[6];
    const float* wf1 = (const float*)d_in[7];
    const float* bf1 = (const float*)d_in[8];
    const float* wf2 = (const float*)d_in[9];
    const float* bf2 = (const float*)d_in[10];
    float* out = (float*)d_out;
    unsigned char* ws = (unsigned char*)d_ws;

    // 1) split weights into MFMA fragments (5120 threads)
    prep_frags<<<dim3(20), dim3(256), 0, stream>>>(w1, w2g, w2s, ws);

    // 2) fused GNN
    const int B = in_sizes[0] / (NNODE * FIN);  // 32768
    gnn_fused<<<dim3(B / GPB), dim3(THREADS), 0, stream>>>(
        x, a, b1, b2, wf1, bf1, wf2, bf2, ws, out);
}

// Round 5
// 209.469 us; speedup vs baseline: 3.1762x; 1.1175x over previous
//
#include <hip/hip_runtime.h>
#include <math.h>

#define NNODE 22
#define FIN 16
#define C1 128
#define C2 64
#define C3 32
#define GPB 2              // graphs per block
#define RROWS (GPB*NNODE)  // 44 valid rows
#define MT 3               // M-tiles for the 44-row combined GEMMs
#define THREADS 256

typedef __attribute__((ext_vector_type(8))) short short8;
typedef __attribute__((ext_vector_type(4))) float f32x4;
typedef __attribute__((ext_vector_type(4))) int i32x4;

// ws layout: W2 frags: 64 frags (wv,nt,kt,h) x 64 lanes x 16B = 65536 B @ 0
//            W1 frags: 16 frags (wv,nt,h)    x 64 lanes x 16B = 16384 B @ 65536
#define WS2_BYTES (64*64*16)
#define WS1_OFF   WS2_BYTES

__device__ __forceinline__ unsigned short f2bf(float f){
    unsigned int u = __builtin_bit_cast(unsigned int, f);
    u += 0x7fffu + ((u >> 16) & 1u);          // RNE
    return (unsigned short)(u >> 16);
}
__device__ __forceinline__ float bf2f(unsigned short h){
    unsigned int u = ((unsigned int)h) << 16;
    return __builtin_bit_cast(float, u);
}
__device__ __forceinline__ void fsplit(float f, unsigned short& hi, unsigned short& lo){
    hi = f2bf(f);
    lo = f2bf(f - bf2f(hi));
}
// H1 swizzle (ushort index): kills bank conflicts on 256B-stride ds_read_b128
__device__ __forceinline__ int hoff(int r, int c){
    return r*C1 + (c ^ ((r & 7) << 3));
}

// ---------------- setup kernel: split weights into MFMA fragments once ----------
__global__ void prep_frags(const float* __restrict__ w1,
                           const float* __restrict__ w2g,
                           const float* __restrict__ w2s,
                           unsigned char* __restrict__ ws)
{
    const int t = blockIdx.x * 256 + threadIdx.x;   // 0..5119
    if (t < 4096) {                                  // W2: f = ((wv*2+nt)*4+kt)*2+h
        const int lane = t & 63, f = t >> 6;
        const int h = f & 1, kt = (f >> 1) & 3, nt = (f >> 3) & 1, wv = f >> 4;
        const int lr = lane & 15, lg = lane >> 4;
        const int col = wv*32 + nt*16 + lr;
        const float* src = (col < C2) ? (w2g + col) : (w2s + (col - C2));
        short8 out;
        #pragma unroll
        for (int e = 0; e < 8; ++e) {
            unsigned short hh, ll;
            fsplit(src[(size_t)(kt*32 + lg*8 + e) * C2], hh, ll);
            out[e] = (short)(h ? ll : hh);
        }
        *(short8*)(ws + (size_t)f*1024 + lane*16) = out;
    } else if (t < 5120) {                           // W1: f = (wv*2+nt)*2+h
        const int u = t - 4096;
        const int lane = u & 63, f = u >> 6;
        const int h = f & 1, nt = (f >> 1) & 1, wv = f >> 2;
        const int lr = lane & 15, lg = lane >> 4;
        short8 out = {0,0,0,0,0,0,0,0};
        if (lane < 32) {
            const int col = wv*32 + nt*16 + lr;
            #pragma unroll
            for (int e = 0; e < 8; ++e) {
                unsigned short hh, ll;
                fsplit(w1[(size_t)(lg*8 + e) * C1 + col], hh, ll);
                out[e] = (short)(h ? ll : hh);
            }
        }
        *(short8*)(ws + WS1_OFF + (size_t)f*1024 + lane*16) = out;
    }
}

// ---------------- main fused kernel ----------------
// R1: fp32 staging (A,X) then Ts (fp32)
union __align__(16) R1u {
    struct { float A[GPB*NNODE*NNODE]; float X[GPB*NNODE*FIN]; } stg;  // 6688 B
    float Ts[RROWS*C2];                                                 // 11264 B
};
// R2: AX hi/lo (phase1->2) then Tg col-major hi/lo (phase3->4)
union __align__(16) R2u {
    struct { unsigned short hi[48][FIN]; unsigned short lo[48][FIN]; } ax;   // 3072 B
    struct { unsigned short h[GPB][C2][32]; unsigned short l[GPB][C2][32]; } tg; // 16384 B
};

__global__ __launch_bounds__(THREADS, 3) void gnn_fused(
    const float* __restrict__ x, const float* __restrict__ a,
    const float* __restrict__ b1, const float* __restrict__ b2,
    const float* __restrict__ wf1, const float* __restrict__ bf1,
    const float* __restrict__ wf2, const float* __restrict__ bf2,
    const unsigned char* __restrict__ ws,
    float* __restrict__ out)
{
    __shared__ R1u R1;                                   // 11264 B
    __shared__ R2u R2;                                   // 16384 B
    __shared__ __align__(16) unsigned short H1h[48*C1];  // 12288 B (swizzled)
    __shared__ __align__(16) unsigned short H1l[48*C1];  // 12288 B
    __shared__ float sPool[GPB][C2];                     // 512 B
    __shared__ float sG1[GPB][C3];                       // 256 B

    const int tid  = threadIdx.x;
    const int lane = tid & 63;
    const int wv   = tid >> 6;
    const int lr   = lane & 15;
    const int lg   = lane >> 4;

    // ---- stage A, X fp32 (float4 coalesced) ----
    const float* ga = a + (size_t)blockIdx.x * (GPB*NNODE*NNODE);
    const float* gx = x + (size_t)blockIdx.x * (GPB*NNODE*FIN);
    if (tid < (GPB*NNODE*NNODE)/4) ((float4*)R1.stg.A)[tid] = ((const float4*)ga)[tid];
    if (tid < (GPB*NNODE*FIN)/4)   ((float4*)R1.stg.X)[tid] = ((const float4*)gx)[tid];
    __syncthreads();

    // ---- build A-operand fragments hi/lo in REGISTERS (graph g1, both mt) ----
    // reused by phase 1 (A@X) and phase 4 (A@Tg). k>=22 zeroed; M rows clamped.
    const int g1 = wv & 1;
    short8 ah[2], al[2];
    #pragma unroll
    for (int m = 0; m < 2; ++m) {
        const int row = (lr + 16*m < NNODE) ? (lr + 16*m) : (NNODE-1);
        short8 fh, fl;
        #pragma unroll
        for (int e = 0; e < 8; ++e) {
            const int k = lg*8 + e;
            const float v = (k < NNODE) ? R1.stg.A[g1*(NNODE*NNODE) + row*NNODE + k] : 0.f;
            unsigned short hh, ll;
            fsplit(v, hh, ll);
            fh[e] = (short)hh; fl[e] = (short)ll;
        }
        ah[m] = fh; al[m] = fl;
    }

    // ---- Phase 1: AX = A @ X via bf16x3 MFMA (wave wv: graph g1, mt = wv>>1) ----
    {
        short8 xh, xl;
        #pragma unroll
        for (int e = 0; e < 8; ++e) {
            const int k = lg*8 + e;
            const float v = (k < NNODE) ? R1.stg.X[g1*(NNODE*FIN) + k*FIN + lr] : 0.f;
            unsigned short hh, ll;
            fsplit(v, hh, ll);
            xh[e] = (short)hh; xl[e] = (short)ll;
        }
        const int m1 = wv >> 1;
        f32x4 d = {0.f,0.f,0.f,0.f};
        d = __builtin_amdgcn_mfma_f32_16x16x32_bf16(ah[m1], xh, d, 0, 0, 0);
        d = __builtin_amdgcn_mfma_f32_16x16x32_bf16(ah[m1], xl, d, 0, 0, 0);
        d = __builtin_amdgcn_mfma_f32_16x16x32_bf16(al[m1], xh, d, 0, 0, 0);
        #pragma unroll
        for (int r = 0; r < 4; ++r) {
            const int n = m1*16 + lg*4 + r;
            if (n < NNODE) {
                unsigned short hh, ll;
                fsplit(d[r], hh, ll);
                R2.ax.hi[g1*NNODE + n][lr] = hh;
                R2.ax.lo[g1*NNODE + n][lr] = ll;
            }
        }
    }
    __syncthreads();

    // ---- Phase 2: H1 = relu(AX @ W1 + b1) via bf16x3 MFMA -> H1 hi/lo LDS ----
    {
        const unsigned char* w1f = ws + WS1_OFF + (size_t)wv*4096 + lane*16;
        const short8 b1h0 = *(const short8*)(w1f + 0);
        const short8 b1l0 = *(const short8*)(w1f + 1024);
        const short8 b1h1 = *(const short8*)(w1f + 2048);
        const short8 b1l1 = *(const short8*)(w1f + 3072);
        const float bb10 = b1[wv*32 + lr];
        const float bb11 = b1[wv*32 + 16 + lr];
        #pragma unroll
        for (int mt = 0; mt < MT; ++mt) {
            short8 axh = {0,0,0,0,0,0,0,0}, axl = {0,0,0,0,0,0,0,0};
            if (lane < 32) {
                axh = *(const short8*)&R2.ax.hi[mt*16 + lr][lg*8];
                axl = *(const short8*)&R2.ax.lo[mt*16 + lr][lg*8];
            }
            f32x4 a0 = {0.f,0.f,0.f,0.f}, a1 = {0.f,0.f,0.f,0.f};
            a0 = __builtin_amdgcn_mfma_f32_16x16x32_bf16(axh, b1h0, a0, 0, 0, 0);
            a0 = __builtin_amdgcn_mfma_f32_16x16x32_bf16(axh, b1l0, a0, 0, 0, 0);
            a0 = __builtin_amdgcn_mfma_f32_16x16x32_bf16(axl, b1h0, a0, 0, 0, 0);
            a1 = __builtin_amdgcn_mfma_f32_16x16x32_bf16(axh, b1h1, a1, 0, 0, 0);
            a1 = __builtin_amdgcn_mfma_f32_16x16x32_bf16(axh, b1l1, a1, 0, 0, 0);
            a1 = __builtin_amdgcn_mfma_f32_16x16x32_bf16(axl, b1h1, a1, 0, 0, 0);
            #pragma unroll
            for (int r = 0; r < 4; ++r) {
                const int row = mt*16 + lg*4 + r;
                if (row < RROWS) {
                    float v0 = a0[r] + bb10; v0 = v0 > 0.f ? v0 : 0.f;
                    float v1 = a1[r] + bb11; v1 = v1 > 0.f ? v1 : 0.f;
                    unsigned short hh, ll;
                    fsplit(v0, hh, ll);
                    H1h[hoff(row, wv*32 + lr)] = hh;
                    H1l[hoff(row, wv*32 + lr)] = ll;
                    fsplit(v1, hh, ll);
                    H1h[hoff(row, wv*32 + 16 + lr)] = hh;
                    H1l[hoff(row, wv*32 + 16 + lr)] = ll;
                }
            }
        }
    }
    __syncthreads();

    // ---- zero R2 (Tg k-pad must be 0, avoids NaN poison); AX is dead now ----
    {
        i32x4* z = (i32x4*)&R2;
        #pragma unroll
        for (int k = 0; k < 4; ++k) z[tid + k*THREADS] = (i32x4){0,0,0,0};
    }

    // ---- Phase 3: T = H1 @ [w2g|w2s] via bf16x3 MFMA (dominant GEMM) ----
    {
        f32x4 acc[MT][2];
        #pragma unroll
        for (int mt = 0; mt < MT; ++mt) {
            acc[mt][0] = (f32x4){0.f,0.f,0.f,0.f};
            acc[mt][1] = (f32x4){0.f,0.f,0.f,0.f};
        }
        const unsigned char* w2f = ws + (size_t)wv*16384 + lane*16;
        const int swz = (lr & 7) << 3;
        #pragma unroll
        for (int kt = 0; kt < 4; ++kt) {
            const unsigned char* wk = w2f + kt*2048;
            const short8 w0h = *(const short8*)(wk + 0);
            const short8 w0l = *(const short8*)(wk + 1024);
            const short8 w1h_ = *(const short8*)(wk + 8192);
            const short8 w1l_ = *(const short8*)(wk + 8192 + 1024);
            #pragma unroll
            for (int mt = 0; mt < MT; ++mt) {
                const int uoff = (mt*16 + lr)*C1 + ((kt*32 + lg*8) ^ swz);
                const short8 hh = *(const short8*)&H1h[uoff];
                const short8 hl = *(const short8*)&H1l[uoff];
                acc[mt][0] = __builtin_amdgcn_mfma_f32_16x16x32_bf16(hh, w0h, acc[mt][0], 0, 0, 0);
                acc[mt][0] = __builtin_amdgcn_mfma_f32_16x16x32_bf16(hh, w0l, acc[mt][0], 0, 0, 0);
                acc[mt][0] = __builtin_amdgcn_mfma_f32_16x16x32_bf16(hl, w0h, acc[mt][0], 0, 0, 0);
                acc[mt][1] = __builtin_amdgcn_mfma_f32_16x16x32_bf16(hh, w1h_, acc[mt][1], 0, 0, 0);
                acc[mt][1] = __builtin_amdgcn_mfma_f32_16x16x32_bf16(hh, w1l_, acc[mt][1], 0, 0, 0);
                acc[mt][1] = __builtin_amdgcn_mfma_f32_16x16x32_bf16(hl, w1h_, acc[mt][1], 0, 0, 0);
            }
        }
        __syncthreads();   // orders: H1 reads done, R2 zero done -> now scatter T
        if (wv < 2) {
            // cols 0..63 = Tg -> col-major hi/lo bf16, zero-padded k (from memset)
            #pragma unroll
            for (int mt = 0; mt < MT; ++mt) {
                #pragma unroll
                for (int r = 0; r < 4; ++r) {
                    const int cr = mt*16 + lg*4 + r;
                    if (cr < RROWS) {
                        const int g = (cr >= NNODE);
                        const int n = cr - g*NNODE;
                        #pragma unroll
                        for (int nt = 0; nt < 2; ++nt) {
                            const int col = wv*32 + nt*16 + lr;
                            unsigned short hh, ll;
                            fsplit(acc[mt][nt][r], hh, ll);
                            R2.tg.h[g][col][n] = hh;
                            R2.tg.l[g][col][n] = ll;
                        }
                    }
                }
            }
        } else {
            // cols 64..127 = Ts -> fp32 row-major [44][64]
            #pragma unroll
            for (int mt = 0; mt < MT; ++mt) {
                #pragma unroll
                for (int r = 0; r < 4; ++r) {
                    const int cr = mt*16 + lg*4 + r;
                    if (cr < RROWS) {
                        #pragma unroll
                        for (int nt = 0; nt < 2; ++nt) {
                            const int c = (wv-2)*32 + nt*16 + lr;
                            R1.Ts[cr*C2 + c] = acc[mt][nt][r];
                        }
                    }
                }
            }
        }
    }
    __syncthreads();

    // ---- Phase 4+5: H2 = relu(A@Tg + Ts + b2); pool via MFMA + shuffle reduce ----
    {
        const int g4 = wv & 1;
        const int ntBase = (wv >> 1) * 2;   // wave covers cols ntBase*16 .. +31
        f32x4 acc4[2][2];
        #pragma unroll
        for (int i = 0; i < 2; ++i) { acc4[i][0] = (f32x4){0,0,0,0}; acc4[i][1] = (f32x4){0,0,0,0}; }
        #pragma unroll
        for (int ntI = 0; ntI < 2; ++ntI) {
            const int col = (ntBase + ntI)*16 + lr;
            const short8 bh = *(const short8*)&R2.tg.h[g4][col][lg*8];
            const short8 bl = *(const short8*)&R2.tg.l[g4][col][lg*8];
            #pragma unroll
            for (int m = 0; m < 2; ++m) {
                acc4[ntI][m] = __builtin_amdgcn_mfma_f32_16x16x32_bf16(ah[m], bh, acc4[ntI][m], 0, 0, 0);
                acc4[ntI][m] = __builtin_amdgcn_mfma_f32_16x16x32_bf16(ah[m], bl, acc4[ntI][m], 0, 0, 0);
                acc4[ntI][m] = __builtin_amdgcn_mfma_f32_16x16x32_bf16(al[m], bh, acc4[ntI][m], 0, 0, 0);
            }
        }
        float pool[2] = {0.f, 0.f};
        #pragma unroll
        for (int ntI = 0; ntI < 2; ++ntI) {
            const int c = (ntBase + ntI)*16 + lr;
            const float bb = b2[c];
            #pragma unroll
            for (int m = 0; m < 2; ++m) {
                #pragma unroll
                for (int r = 0; r < 4; ++r) {
                    const int n = m*16 + lg*4 + r;
                    if (n < NNODE) {
                        float v = acc4[ntI][m][r] + R1.Ts[(g4*NNODE + n)*C2 + c] + bb;
                        pool[ntI] += (v > 0.f ? v : 0.f);
                    }
                }
            }
            pool[ntI] += __shfl_xor(pool[ntI], 16);
            pool[ntI] += __shfl_xor(pool[ntI], 32);
        }
        if (lane < 16) {
            sPool[g4][(ntBase + 0)*16 + lr] = pool[0];
            sPool[g4][(ntBase + 1)*16 + lr] = pool[1];
        }
    }
    __syncthreads();

    // ---- Phase 6: head ----
    if (tid < GPB*C3) {
        const int g = tid >> 5, j = tid & 31;
        float s = bf1[j];
        #pragma unroll
        for (int c = 0; c < C2; ++c) s += sPool[g][c] * wf1[c*C3 + j];
        sG1[g][j] = s > 0.f ? s : 0.f;
    }
    __syncthreads();
    if (tid < GPB) {
        float s = bf2[0];
        #pragma unroll
        for (int j = 0; j < C3; ++j) s += sG1[tid][j] * wf2[j];
        out[(size_t)blockIdx.x*GPB + tid] = 1.f / (1.f + expf(-s));
    }
}

extern "C" void kernel_launch(void* const* d_in, const int* in_sizes, int n_in,
                              void* d_out, int out_size, void* d_ws, size_t ws_size,
                              hipStream_t stream) {
    const float* x   = (const float*)d_in[0];
    const float* a   = (const float*)d_in[1];
    const float* w1  = (const float*)d_in[2];
    const float* b1  = (const float*)d_in[3];
    const float* w2g = (const float*)d_in[4];
    const float* w2s = (const float*)d_in[5];
    const float* b2  = (const float*)d_in[6];
    const float* wf1 = (const float*)d_in[7];
    const float* bf1 = (const float*)d_in[8];
    const float* wf2 = (const float*)d_in[9];
    const float* bf2 = (const float*)d_in[10];
    float* out = (float*)d_out;
    unsigned char* ws = (unsigned char*)d_ws;

    prep_frags<<<dim3(20), dim3(256), 0, stream>>>(w1, w2g, w2s, ws);

    const int B = in_sizes[0] / (NNODE * FIN);  // 32768
    gnn_fused<<<dim3(B / GPB), dim3(THREADS), 0, stream>>>(
        x, a, b1, b2, wf1, bf1, wf2, bf2, ws, out);
}